// Round 13
// baseline (94.826 us; speedup 1.0000x reference)
//
#include <hip/hip_runtime.h>
#include <stdint.h>

#define IN_F 2048
#define OUT_F 2048
#define N_ROWS 8192

// ---- GEMM geometry: 256x256 tile, BK=32, 8 waves (2Mx4N).
// A: DMA (global_load_lds) from pre-tiled swizzled image, 4-deep LDS.
// B: direct-to-VGPR from pre-tiled image (ping-pong, depth-1 prefetch).
#define BM 256
#define BN 256
#define BK 32
#define NT (IN_F / BK)             // 64 K-steps
#define TM_TILES (N_ROWS / BM)     // 32
#define TN_TILES (OUT_F / BN)      // 8
#define NWG (TM_TILES * TN_TILES)  // 256 == #CUs
#define TILE_SHORTS (BM * BK)      // 8192 shorts = 16 KiB per (tile,kstep)

typedef __bf16 bf16x8 __attribute__((ext_vector_type(8)));
typedef float f32x4 __attribute__((ext_vector_type(4)));
typedef unsigned short ushortx8 __attribute__((ext_vector_type(8)));

__device__ __forceinline__ unsigned short f2bf(float f) {
  unsigned u = __builtin_bit_cast(unsigned, f);
  u += 0x7FFFu + ((u >> 16) & 1u);
  return (unsigned short)(u >> 16);
}

__device__ __forceinline__ void async16(void* lds, const void* g) {
  __builtin_amdgcn_global_load_lds(
      (const __attribute__((address_space(1))) void*)(uintptr_t)g,
      (__attribute__((address_space(3))) void*)(uint32_t)(uintptr_t)lds,
      16, 0, 0);
}

__device__ __forceinline__ bf16x8 ld8(const unsigned short* p) {
  return __builtin_bit_cast(bf16x8, *reinterpret_cast<const ushortx8*>(p));
}

// ---- prep: pre-tiled staging images.
// A image (SWIZZLED, for LDS): chunk t in [0,1024) of tile (R*64+T):
//   r=t>>2, slot s=t&3 holds k-group ga = s ^ ((r>>1)&3);
//   AbT[tile*8192 + t*8 + j] = bf16(A[R*256 + r][T*32 + ga*8 + j])
// B image (LINEAR, for direct reg loads): slot s holds k-group s;
//   BtT[tile*8192 + t*8 + e] = Ht[Ct*256 + r][T*32 + s*8 + e],
//   Ht[b][a] = s(q,c) * W[u][(q^c)*512 + v]  (q=a&3,u=a>>2,c=b&3,v=b>>2)
__global__ __launch_bounds__(256) void k_prep(const float* __restrict__ A,
                                              unsigned short* __restrict__ AbT,
                                              const float* __restrict__ W,
                                              unsigned short* __restrict__ BtT) {
  const int bid = blockIdx.x;
  if (bid < 8192) {
    const int tile = bid >> 2;                       // R*64 + T
    const int t = ((bid & 3) << 8) + threadIdx.x;    // chunk 0..1023
    const int r = t >> 2;
    const int ga = (t & 3) ^ ((r >> 1) & 3);
    const int R = tile >> 6, T = tile & 63;
    const float* src = A + (size_t)(R * 256 + r) * IN_F + T * 32 + ga * 8;
    const float4 v0 = *reinterpret_cast<const float4*>(src);
    const float4 v1 = *reinterpret_cast<const float4*>(src + 4);
    ushortx8 o;
    o[0] = f2bf(v0.x); o[1] = f2bf(v0.y); o[2] = f2bf(v0.z); o[3] = f2bf(v0.w);
    o[4] = f2bf(v1.x); o[5] = f2bf(v1.y); o[6] = f2bf(v1.z); o[7] = f2bf(v1.w);
    *reinterpret_cast<ushortx8*>(AbT + (size_t)tile * 8192 + t * 8) = o;
  } else {
    const int bb = bid - 8192;                       // 0..2047
    const int tile = bb >> 2;                        // Ct*64 + T
    const int t = ((bb & 3) << 8) + threadIdx.x;
    const int r = t >> 2, s = t & 3;
    const int Ct = tile >> 6, T = tile & 63;
    const int b = Ct * 256 + r;
    const int c = b & 3, v = b >> 2;
    const int a0 = T * 32 + s * 8;
    ushortx8 o;
#pragma unroll
    for (int e = 0; e < 8; ++e) {
      const int a = a0 + e;
      const int q = a & 3, u = a >> 2;
      float w = W[(size_t)u * OUT_F + ((q ^ c) << 9) + v];
      if ((0x284E >> ((q << 2) | c)) & 1) w = -w;
      o[e] = f2bf(w);
    }
    *reinterpret_cast<ushortx8*>(BtT + (size_t)tile * 8192 + t * 8) = o;
  }
}

// ---- main GEMM: C = A(bf16) @ Ht^T + bias ----
__global__ __launch_bounds__(512, 2) void k_gemm(const unsigned short* __restrict__ AbT,
                                                 const unsigned short* __restrict__ BtT,
                                                 const float* __restrict__ bias,
                                                 float* __restrict__ C) {
  __shared__ __align__(16) unsigned short lds[4 * TILE_SHORTS];  // 64 KiB (A only)

  const int tid = threadIdx.x;
  const int lane = tid & 63;
  const int w = tid >> 6;   // wave 0..7
  const int wm = w >> 2;    // 0..1 -> rows wm*128..+128
  const int wn = w & 3;     // 0..3 -> cols wn*64..+64
  const int fr = lane & 15;
  const int g = lane >> 4;  // k-group 0..3 (8 bf16 each)

  // XCD-bijective swizzle: 256 wgs, 32 contiguous tiles per XCD
  const int wg = blockIdx.x;
  const int swz = (wg & 7) * (NWG >> 3) + (wg >> 3);
  const int tm = swz >> 3;
  const int tn = swz & 7;
  const int row0 = tm * BM, col0 = tn * BN;

  // ---- A staging: pre-tiled image, 2 x 1KB linear DMA per wave per step
  const unsigned short* baseA = AbT + (size_t)tm * 64 * 8192;
  const int tOff0 = (w * 128 + lane) * 8;  // shorts
  const int tOff1 = tOff0 + 512;           // +64 chunks

#define ASTG(T)                                                    \
  do {                                                             \
    unsigned short* d_ = &lds[((T) & 3) * TILE_SHORTS];            \
    const unsigned short* s_ = baseA + (size_t)(T) * 8192;         \
    async16(d_ + tOff0, s_ + tOff0);                               \
    async16(d_ + tOff1, s_ + tOff1);                               \
  } while (0)

  // ---- B fragment pointers (global, linear image): per (n, step) a wave
  // reads one coalesced 1KB region (16 rows x 64B).
  const unsigned short* bp[4];
#pragma unroll
  for (int n = 0; n < 4; ++n) {
    const int r = wn * 64 + n * 16 + fr;
    bp[n] = BtT + (size_t)tn * 64 * 8192 + r * 32 + g * 8;
  }

  // ---- A fragment LDS read offsets (shorts), swizzle matches A image
  int offA[8];
#pragma unroll
  for (int m = 0; m < 8; ++m) {
    const int r = wm * 128 + m * 16 + fr;
    offA[m] = r * BK + ((g ^ ((r >> 1) & 3)) << 3);
  }

  f32x4 acc[8][4] = {};
  bf16x8 bgE[4], bgO[4];  // B ping-pong (static indexing only)

#define MFMA_(a_, b_, c_) __builtin_amdgcn_mfma_f32_16x16x32_bf16(a_, b_, c_, 0, 0, 0)
#define FENCE_ __builtin_amdgcn_sched_barrier(0)

  // Step T: barrier [A(T) block-wide ready: each wave's pos5-wait at T-1
  // retired its own A(T) DMA] -> 8 ds_read A(T) -> load B(T+1)->regs ->
  // DMA A(T+3) [into buf (T-1)&3: WAR-safe, reads of it drained pre-barrier]
  // -> vmcnt(N) [retires B(T) and A(T+1), in-order queue: 2 A-ops + 4 B-ops
  // per step -> steady N=8; tail 6/4/0] -> 32 MFMA.
#define STEP(T, BGC, BGN, DOB, DOA, VMSTR)                                    \
  do {                                                                        \
    __builtin_amdgcn_s_barrier();                                             \
    FENCE_;                                                                   \
    const unsigned short* a_ = &lds[((T) & 3) * TILE_SHORTS];                 \
    bf16x8 af[8];                                                             \
    _Pragma("unroll") for (int m = 0; m < 8; ++m) af[m] = ld8(a_ + offA[m]);  \
    FENCE_;                                                                   \
    if (DOB) {                                                                \
      _Pragma("unroll") for (int n = 0; n < 4; ++n)                           \
        BGN[n] = ld8(bp[n] + (size_t)((T) + 1) * 8192);                       \
    }                                                                         \
    FENCE_;                                                                   \
    if (DOA) ASTG((T) + 3);                                                   \
    FENCE_;                                                                   \
    asm volatile("s_waitcnt vmcnt(" VMSTR ")" ::: "memory");                  \
    __builtin_amdgcn_s_setprio(1);                                            \
    _Pragma("unroll") for (int m = 0; m < 8; ++m)                             \
      _Pragma("unroll") for (int n = 0; n < 4; ++n)                           \
        acc[m][n] = MFMA_(af[m], BGC[n], acc[m][n]);                          \
    __builtin_amdgcn_s_setprio(0);                                            \
    FENCE_;                                                                   \
  } while (0)

  // ---- prologue: A(0) DMA, B(0) regs, A(1),A(2) DMA; vmcnt(8) retires A(0)
  ASTG(0);
  FENCE_;
#pragma unroll
  for (int n = 0; n < 4; ++n) bgE[n] = ld8(bp[n]);
  FENCE_;
  ASTG(1);
  ASTG(2);
  FENCE_;
  asm volatile("s_waitcnt vmcnt(8)" ::: "memory");

  // steady: steps 0..59 (B(1..60), A(3..62))
#pragma unroll 1
  for (int t = 0; t < NT - 4; t += 2) {
    STEP(t, bgE, bgO, 1, 1, "8");
    STEP(t + 1, bgO, bgE, 1, 1, "8");
  }
  // tail: 60 (B61, A63), 61 (B62), 62 (B63), 63 (drain)
  STEP(NT - 4, bgE, bgO, 1, 1, "8");
  STEP(NT - 3, bgO, bgE, 1, 0, "6");
  STEP(NT - 2, bgE, bgO, 1, 0, "4");
  STEP(NT - 1, bgO, bgE, 0, 0, "0");

#undef STEP
#undef ASTG

  // ---- epilogue: C/D layout col=lane&15, row=(lane>>4)*4+reg ----
  const int g4 = g << 2;
  float bv[4];
#pragma unroll
  for (int n = 0; n < 4; ++n) bv[n] = bias[col0 + wn * 64 + n * 16 + fr];
#pragma unroll
  for (int m = 0; m < 8; ++m) {
#pragma unroll
    for (int e = 0; e < 4; ++e) {
      const int row = row0 + wm * 128 + m * 16 + g4 + e;
      float* cp = C + (size_t)row * OUT_F + col0 + wn * 64 + fr;
#pragma unroll
      for (int n = 0; n < 4; ++n) cp[n * 16] = acc[m][n][e] + bv[n];
    }
  }
}

// ---- fallback if workspace too small: naive fp32 ----
__global__ __launch_bounds__(256) void k_naive(const float* __restrict__ A,
                                               const float* __restrict__ W,
                                               const float* __restrict__ bias,
                                               float* __restrict__ C) {
  const int idx = blockIdx.x * 256 + threadIdx.x;
  const int m = idx >> 11;
  const int b = idx & (OUT_F - 1);
  const int c = b & 3, v = b >> 2;
  float acc = 0.f;
  const float* arow = A + (size_t)m * IN_F;
  for (int a = 0; a < IN_F; ++a) {
    const int q = a & 3, u = a >> 2;
    float h = W[(size_t)u * OUT_F + ((q ^ c) << 9) + v];
    if ((0x284E >> ((q << 2) | c)) & 1) h = -h;
    acc += arow[a] * h;
  }
  C[idx] = acc + bias[b];
}

extern "C" void kernel_launch(void* const* d_in, const int* in_sizes, int n_in,
                              void* d_out, int out_size, void* d_ws, size_t ws_size,
                              hipStream_t stream) {
  (void)in_sizes; (void)n_in; (void)out_size;
  const float* inp  = (const float*)d_in[0];
  const float* w    = (const float*)d_in[1];
  const float* bias = (const float*)d_in[2];
  float* out = (float*)d_out;

  const size_t needA = (size_t)N_ROWS * IN_F * sizeof(unsigned short);  // 32 MiB
  const size_t needB = (size_t)IN_F * OUT_F * sizeof(unsigned short);   //  8 MiB
  if (ws_size < needA + needB) {
    k_naive<<<(N_ROWS * OUT_F) / 256, 256, 0, stream>>>(inp, w, bias, out);
    return;
  }

  unsigned short* AbT = (unsigned short*)d_ws;
  unsigned short* BtT = AbT + (size_t)N_ROWS * IN_F;

  k_prep<<<8192 + 2048, 256, 0, stream>>>(inp, AbT, w, BtT);
  k_gemm<<<NWG, 512, 0, stream>>>(AbT, BtT, bias, out);
}

// Round 14
// 86.045 us; speedup vs baseline: 1.1021x; 1.1021x over previous
//
#include <hip/hip_runtime.h>
#include <stdint.h>

#define IN_F 2048
#define OUT_F 2048
#define N_ROWS 8192

// ---- GEMM geometry: 256x256 tile, BK=32, 8 waves (2Mx4N), 4-deep LDS,
// r11 structure (pre-tiled images, linear DMA) + B-fragment ping-pong
// (breaks the cross-step WAR that serialized LDS reads behind MFMA drain).
#define BM 256
#define BN 256
#define BK 32
#define NT (IN_F / BK)             // 64 K-steps
#define TM_TILES (N_ROWS / BM)     // 32
#define TN_TILES (OUT_F / BN)      // 8
#define NWG (TM_TILES * TN_TILES)  // 256 == #CUs
#define TILE_SHORTS (BM * BK)      // 8192 shorts = 16 KiB per (tile,kstep)
#define BUF_SHORTS (2 * TILE_SHORTS)

typedef __bf16 bf16x8 __attribute__((ext_vector_type(8)));
typedef float f32x4 __attribute__((ext_vector_type(4)));
typedef unsigned short ushortx8 __attribute__((ext_vector_type(8)));

__device__ __forceinline__ unsigned short f2bf(float f) {
  unsigned u = __builtin_bit_cast(unsigned, f);
  u += 0x7FFFu + ((u >> 16) & 1u);
  return (unsigned short)(u >> 16);
}

__device__ __forceinline__ void async16(void* lds, const void* g) {
  __builtin_amdgcn_global_load_lds(
      (const __attribute__((address_space(1))) void*)(uintptr_t)g,
      (__attribute__((address_space(3))) void*)(uint32_t)(uintptr_t)lds,
      16, 0, 0);
}

__device__ __forceinline__ bf16x8 ld8(const unsigned short* p) {
  return __builtin_bit_cast(bf16x8, *reinterpret_cast<const ushortx8*>(p));
}

// ---- prep: build pre-tiled, pre-swizzled staging images (as r11).
// Chunk t in [0,1024) of tile (X*64+T): row r=t>>2, slot s=t&3 holds
// k-group ga = s ^ ((r>>1)&3)  (same swizzle the GEMM reads with).
__global__ __launch_bounds__(256) void k_prep(const float* __restrict__ A,
                                              unsigned short* __restrict__ AbT,
                                              const float* __restrict__ W,
                                              unsigned short* __restrict__ BtT) {
  const int bid = blockIdx.x;
  if (bid < 8192) {
    const int tile = bid >> 2;                       // R*64 + T
    const int t = ((bid & 3) << 8) + threadIdx.x;    // chunk 0..1023
    const int r = t >> 2;
    const int ga = (t & 3) ^ ((r >> 1) & 3);
    const int R = tile >> 6, T = tile & 63;
    const float* src = A + (size_t)(R * 256 + r) * IN_F + T * 32 + ga * 8;
    const float4 v0 = *reinterpret_cast<const float4*>(src);
    const float4 v1 = *reinterpret_cast<const float4*>(src + 4);
    ushortx8 o;
    o[0] = f2bf(v0.x); o[1] = f2bf(v0.y); o[2] = f2bf(v0.z); o[3] = f2bf(v0.w);
    o[4] = f2bf(v1.x); o[5] = f2bf(v1.y); o[6] = f2bf(v1.z); o[7] = f2bf(v1.w);
    *reinterpret_cast<ushortx8*>(AbT + (size_t)tile * 8192 + t * 8) = o;
  } else {
    const int bb = bid - 8192;                       // 0..2047
    const int tile = bb >> 2;                        // Ct*64 + T, 0..511
    const int t = ((bb & 3) << 8) + threadIdx.x;
    const int r = t >> 2;
    const int ga = (t & 3) ^ ((r >> 1) & 3);
    const int Ct = tile >> 6, T = tile & 63;
    const int b = Ct * 256 + r;
    const int c = b & 3, v = b >> 2;
    const int a0 = T * 32 + ga * 8;
    ushortx8 o;
#pragma unroll
    for (int e = 0; e < 8; ++e) {
      const int a = a0 + e;
      const int q = a & 3, u = a >> 2;
      float w = W[(size_t)u * OUT_F + ((q ^ c) << 9) + v];
      if ((0x284E >> ((q << 2) | c)) & 1) w = -w;
      o[e] = f2bf(w);
    }
    *reinterpret_cast<ushortx8*>(BtT + (size_t)tile * 8192 + t * 8) = o;
  }
}

// ---- main GEMM: C = A(bf16) @ Ht^T + bias ----
__global__ __launch_bounds__(512, 2) void k_gemm(const unsigned short* __restrict__ AbT,
                                                 const unsigned short* __restrict__ BtT,
                                                 const float* __restrict__ bias,
                                                 float* __restrict__ C) {
  __shared__ __align__(16) unsigned short lds[4 * BUF_SHORTS];  // 128 KiB

  const int tid = threadIdx.x;
  const int lane = tid & 63;
  const int w = tid >> 6;   // wave 0..7
  const int wm = w >> 2;    // 0..1 -> rows wm*128..+128
  const int wn = w & 3;     // 0..3 -> cols wn*64..+64
  const int fr = lane & 15;
  const int g = lane >> 4;  // k-group 0..3 (8 bf16 each)

  // XCD-bijective swizzle: 256 wgs, 32 contiguous tiles per XCD
  const int wg = blockIdx.x;
  const int swz = (wg & 7) * (NWG >> 3) + (wg >> 3);
  const int tm = swz >> 3;
  const int tn = swz & 7;
  const int row0 = tm * BM, col0 = tn * BN;

  // ---- staging: pre-tiled images -> fully linear DMA (2x1KB A + 2x1KB B/wave)
  const unsigned short* baseA = AbT + (size_t)tm * 64 * 8192;
  const unsigned short* baseB = BtT + (size_t)tn * 64 * 8192;
  const int tOff0 = (w * 128 + lane) * 8;        // shorts
  const int tOff1 = (w * 128 + 64 + lane) * 8;

#define STAGE(T)                                                   \
  do {                                                             \
    unsigned short* base_ = &lds[((T) & 3) * BUF_SHORTS];          \
    const unsigned short* sa_ = baseA + (size_t)(T) * 8192;        \
    const unsigned short* sb_ = baseB + (size_t)(T) * 8192;        \
    async16(base_ + tOff0, sa_ + tOff0);                           \
    async16(base_ + tOff1, sa_ + tOff1);                           \
    async16(base_ + TILE_SHORTS + tOff0, sb_ + tOff0);             \
    async16(base_ + TILE_SHORTS + tOff1, sb_ + tOff1);             \
  } while (0)

  // ---- fragment read offsets (shorts), read swizzle = baked image swizzle
  int offA[8], offB[4];
#pragma unroll
  for (int m = 0; m < 8; ++m) {
    const int r = wm * 128 + m * 16 + fr;
    offA[m] = r * BK + ((g ^ ((r >> 1) & 3)) << 3);
  }
#pragma unroll
  for (int n = 0; n < 4; ++n) {
    const int r = wn * 64 + n * 16 + fr;
    offB[n] = TILE_SHORTS + r * BK + ((g ^ ((r >> 1) & 3)) << 3);
  }

  f32x4 acc[8][4] = {};
  bf16x8 bgE[4], bgO[4];  // B-fragment ping-pong by step parity (WAR breaker)

#define MFMA_(a_, b_, c_) __builtin_amdgcn_mfma_f32_16x16x32_bf16(a_, b_, c_, 0, 0, 0)

  // prologue: 3 tiles in flight (12 loads/wave)
  STAGE(0);
  STAGE(1);
  STAGE(2);

  // Step T: vmcnt(N) [stage T retired] -> barrier -> 8 af reads (af[m] WAR
  // resolves at cluster m of T-1: pipelined) -> 4 bg reads into parity regs
  // (no WAR vs T-1: other parity) -> STAGE(T+3) -> m-major MFMA (af[m] dead
  // after cluster m). Reads of step T+1 flow while MFMA(T) drains.
#define STEP(T, BG_, VMSTR, DOSTAGE)                                          \
  do {                                                                        \
    asm volatile("s_waitcnt vmcnt(" VMSTR ")" ::: "memory");                  \
    __builtin_amdgcn_s_barrier();                                             \
    __builtin_amdgcn_sched_barrier(0);                                        \
    const unsigned short* b_ = &lds[((T) & 3) * BUF_SHORTS];                  \
    bf16x8 af[8];                                                             \
    _Pragma("unroll") for (int m = 0; m < 8; ++m) af[m] = ld8(b_ + offA[m]);  \
    _Pragma("unroll") for (int n = 0; n < 4; ++n) BG_[n] = ld8(b_ + offB[n]); \
    if (DOSTAGE) STAGE((T) + 3);                                              \
    __builtin_amdgcn_s_setprio(1);                                            \
    _Pragma("unroll") for (int m = 0; m < 8; ++m)                             \
      _Pragma("unroll") for (int n = 0; n < 4; ++n)                           \
        acc[m][n] = MFMA_(af[m], BG_[n], acc[m][n]);                          \
    __builtin_amdgcn_s_setprio(0);                                            \
  } while (0)

  // steady: T = 0..59 (stages 3..62)
#pragma unroll 1
  for (int t = 0; t < NT - 4; t += 2) {
    STEP(t, bgE, "8", true);
    STEP(t + 1, bgO, "8", true);
  }
  // tail: T=60 stages 63; 61/62/63 drain 8/4/0
  STEP(NT - 4, bgE, "8", true);
  STEP(NT - 3, bgO, "8", false);
  STEP(NT - 2, bgE, "4", false);
  STEP(NT - 1, bgO, "0", false);

#undef STEP
#undef STAGE

  // ---- epilogue: C/D layout col=lane&15, row=(lane>>4)*4+reg ----
  const int g4 = g << 2;
  float bv[4];
#pragma unroll
  for (int n = 0; n < 4; ++n) bv[n] = bias[col0 + wn * 64 + n * 16 + fr];
#pragma unroll
  for (int m = 0; m < 8; ++m) {
#pragma unroll
    for (int e = 0; e < 4; ++e) {
      const int row = row0 + wm * 128 + m * 16 + g4 + e;
      float* cp = C + (size_t)row * OUT_F + col0 + wn * 64 + fr;
#pragma unroll
      for (int n = 0; n < 4; ++n) cp[n * 16] = acc[m][n][e] + bv[n];
    }
  }
}

// ---- fallback if workspace too small: naive fp32 ----
__global__ __launch_bounds__(256) void k_naive(const float* __restrict__ A,
                                               const float* __restrict__ W,
                                               const float* __restrict__ bias,
                                               float* __restrict__ C) {
  const int idx = blockIdx.x * 256 + threadIdx.x;
  const int m = idx >> 11;
  const int b = idx & (OUT_F - 1);
  const int c = b & 3, v = b >> 2;
  float acc = 0.f;
  const float* arow = A + (size_t)m * IN_F;
  for (int a = 0; a < IN_F; ++a) {
    const int q = a & 3, u = a >> 2;
    float h = W[(size_t)u * OUT_F + ((q ^ c) << 9) + v];
    if ((0x284E >> ((q << 2) | c)) & 1) h = -h;
    acc += arow[a] * h;
  }
  C[idx] = acc + bias[b];
}

extern "C" void kernel_launch(void* const* d_in, const int* in_sizes, int n_in,
                              void* d_out, int out_size, void* d_ws, size_t ws_size,
                              hipStream_t stream) {
  (void)in_sizes; (void)n_in; (void)out_size;
  const float* inp  = (const float*)d_in[0];
  const float* w    = (const float*)d_in[1];
  const float* bias = (const float*)d_in[2];
  float* out = (float*)d_out;

  const size_t needA = (size_t)N_ROWS * IN_F * sizeof(unsigned short);  // 32 MiB
  const size_t needB = (size_t)IN_F * OUT_F * sizeof(unsigned short);   //  8 MiB
  if (ws_size < needA + needB) {
    k_naive<<<(N_ROWS * OUT_F) / 256, 256, 0, stream>>>(inp, w, bias, out);
    return;
  }

  unsigned short* AbT = (unsigned short*)d_ws;
  unsigned short* BtT = AbT + (size_t)N_ROWS * IN_F;

  k_prep<<<8192 + 2048, 256, 0, stream>>>(inp, AbT, w, BtT);
  k_gemm<<<NWG, 512, 0, stream>>>(AbT, BtT, bias, out);
}